// Round 7
// baseline (686.042 us; speedup 1.0000x reference)
//
#include <hip/hip_runtime.h>

typedef _Float16 half8 __attribute__((ext_vector_type(8)));
typedef float f32x4 __attribute__((ext_vector_type(4)));
typedef unsigned int u32;
typedef unsigned int u32x4 __attribute__((ext_vector_type(4)));

#define SC_AGENT __HIP_MEMORY_SCOPE_AGENT

// Problem: B=16, T=64, L=64, H=256. K=2H=512, N=4H=1024.
//
// Round 7: single merged poll round (data + gate + backpressure in ONE batched
// issue -> one vmcnt), own-slice h via LDS (never round-trips IC).
//
//   h words: [h f16 | tag16], tag16 = (ep<<7)|t (t=0..63; 127 = h(l,-1) init).
//   All cross-WG traffic sc0 sc1 (IC truth) -- placement-independent, G16-safe.
//   Single store per word (R5 showed dual plain+sc stores ping-pong).
//
//   Step: merged-poll -> barrier -> GEMM -> barrier -> shfl-transpose ->
//         epilogue -> publish (global store for siblings/next layer +
//         ds_write into next step's own aLds slots).
//
//   Staging layout identity (thread wv,lane; s=lane>>4, m=lane&15):
//     k-high granule (i3,g): units u = 32*wv + 128*i3 + 8*s + 4*g + j, j=0..3
//     aLds f16 slot for (m,u): [(8+(u>>5))*64 + (((u&31)>>3)<<4 | m)]*8 + (u&7)
//   Own slice (u in [64r,64r+64)) is written by publish-side ds_write
//   (each thread owns (u_q[q], m_own), all in own slice); pend bits
//   pre-cleared via ownMask. t=0 seeded by prologue ds_write of init_state.
//
// ws: prog[256] u32 @0 (idx l*4+r); epoch u32 @4096; Hw4 @64KB:
//     u32[2 slots][64 l][16 b][256 u] = 2 MB.
constexpr size_t OFF_PROG  = 0;
constexpr size_t OFF_EPOCH = 4096;
constexpr size_t OFF_H     = 65536;
constexpr size_t S4 = (size_t)64 * 16 * 256;  // u32 words per slot

__device__ __forceinline__ float sigm(float v) { return 1.0f / (1.0f + __expf(-v)); }
__device__ __forceinline__ float tanh_(float v) { return 1.0f - 2.0f / (__expf(2.0f * v) + 1.0f); }
__device__ __forceinline__ u32 min4(u32x4 v) {
  u32 a = v[0] < v[1] ? v[0] : v[1];
  u32 b = v[2] < v[3] ? v[2] : v[3];
  return a < b ? a : b;
}

// Async IC loads: MUST be followed by s_waitcnt vmcnt(0) + sched_barrier(0)
// before reading dst (rule #18).
#define GLD4(dst, base, OFS)                                                  \
  asm volatile("global_load_dwordx4 %0, %1, off offset:" #OFS " sc0 sc1"      \
               : "=v"(dst) : "v"(base))

// ---------------- epoch bump: ep cycles 1..511 ----------------
__global__ void bump_epoch(char* ws) {
  u32* ep = (u32*)(ws + OFF_EPOCH);
  u32 v = __hip_atomic_load(ep, __ATOMIC_RELAXED, SC_AGENT);
  u32 n = (v + 1) & 0x1FFu;
  if (n == 0) n = 1;
  __hip_atomic_store(ep, n, __ATOMIC_RELAXED, SC_AGENT);
}

// ---------------- init: prog=epb-1, slot0 tag 0 (never matches, ep>=1),
// slot1 = h(l,-1) with tag epb|127 ----------------
__global__ void init_ws(const float* __restrict__ init_state, char* ws) {
  u32* prog = (u32*)(ws + OFF_PROG);
  u32* Hw4 = (u32*)(ws + OFF_H);
  const u32 ep = __hip_atomic_load((u32*)(ws + OFF_EPOCH), __ATOMIC_RELAXED, SC_AGENT);
  const u32 epb = (ep & 0x1FFu) << 7;  // ep in [1,511] -> epb >= 128
  const int tid = blockIdx.x * 256 + threadIdx.x;  // 65536 threads
  if (tid < 256) prog[tid] = epb - 1u;  // < epb|t for all t
  const u32 tagInit = (epb | 127u) << 16;
  for (int e = tid; e < 64 * 16 * 256; e += 65536) {
    const int u = e & 255, b = (e >> 8) & 15, l = e >> 12;
    const size_t idx = ((size_t)l * 16 + b) * 256 + u;
    Hw4[idx] = 0u;  // slot0: tag 0, never matches
    union { _Float16 f; unsigned short s; } hv;
    hv.f = (_Float16)init_state[((l * 2 + 1) * 16 + b) * 256 + u];
    Hw4[S4 + idx] = (u32)hv.s | tagInit;
  }
}

// ---------------- main: 256 WGs = (layer l = wg>>2, slice r = wg&3) ----------------
__global__ __launch_bounds__(256, 1) void lstm_mfma(
    const float* __restrict__ x, const float* __restrict__ init_state,
    const float* __restrict__ W, const float* __restrict__ bias,
    float* __restrict__ out, char* ws) {
  u32* prog = (u32*)(ws + OFF_PROG);
  u32* Hw4 = (u32*)(ws + OFF_H);

  const int tid = threadIdx.x;
  const int wg = blockIdx.x;
  const int l = wg >> 2, r = wg & 3;
  const int wv = tid >> 6, lane = tid & 63;

  const u32 epb = (__hip_atomic_load((u32*)(ws + OFF_EPOCH), __ATOMIC_RELAXED,
                                     SC_AGENT) & 0x1FFu) << 7;

  __shared__ alignas(16) _Float16 aLds[16 * 64 * 8];  // A-frags: [kb][lane][8], 16 KB

  // ---- W slice -> registers ----
  half8 wreg[64];
#pragma unroll
  for (int q = 0; q < 4; ++q) {
    const int nl = (wv * 4 + q) * 16 + (lane & 15);
    const int col = (nl & 3) * 256 + r * 64 + (nl >> 2);
#pragma unroll
    for (int kb = 0; kb < 16; ++kb) {
      const int k0 = kb * 32 + (lane >> 4) * 8;
      const float* src = W + (size_t)k0 * 1024 + col;
      half8 hv;
#pragma unroll
      for (int jj = 0; jj < 8; ++jj) hv[jj] = (_Float16)src[(size_t)jj * 1024];
      wreg[q * 16 + kb] = hv;
    }
  }

  // ---- per-thread epilogue identity (post-butterfly): per q-tile this thread
  // owns (unit u_q, batch m_own), all 4 gates in-lane.
  const int m_own = (lane >> 4) * 4 + (lane & 3);
  int gu_q[4];
  float creg[4], bI[4], bJ[4], bF[4], bO[4];
#pragma unroll
  for (int q = 0; q < 4; ++q) {
    const int u_q = (wv * 4 + q) * 4 + ((lane & 15) >> 2);  // unit in slice
    gu_q[q] = r * 64 + u_q;
    creg[q] = init_state[((l * 2 + 0) * 16 + m_own) * 256 + gu_q[q]];
    bI[q] = bias[0 * 256 + gu_q[q]];
    bJ[q] = bias[1 * 256 + gu_q[q]];
    bF[q] = bias[2 * 256 + gu_q[q]];
    bO[q] = bias[3 * 256 + gu_q[q]];
  }

  // ---- prologue: seed own-slice h(l,-1) into aLds (staging-layout inverse) ----
#pragma unroll
  for (int q = 0; q < 4; ++q) {
    const int gu = gu_q[q];
    const float h0 = init_state[((l * 2 + 1) * 16 + m_own) * 256 + gu];
    aLds[(size_t)((8 + (gu >> 5)) * 64 + ((((gu & 31) >> 3) << 4) | m_own)) * 8 +
         (gu & 7)] = (_Float16)h0;
  }

  // ---- staging geometry ----
  const int m = lane & 15;
  const int ksub = (lane >> 4) * 8;  // k-offset within a kb tile
  // own-slice pend bits (supplied via ds_write, never polled):
  const u32 ownMask = ((wv >> 1) == r) ? 0x30u
                    : (((wv + 4) >> 1) == r) ? 0xC0u : 0u;

  u32 plCache = 0, bpCache = 0;  // cached prog gates (monotone within launch)
  u32* const plBase = &prog[(l > 0 ? l - 1 : 0) * 4];
  u32* const bpBase = &prog[(l < 63 ? l + 1 : 63) * 4];

  for (int t = 0; t < 64; ++t) {
    const int slotCur = t & 1, slotPrev = (t + 1) & 1;
    const u32 expIn = epb | (u32)t;                               // h(l-1,t)
    const u32 expOwn = (t > 0) ? (epb | (u32)(t - 1)) : (epb | 127u);

    // ---- l==0: x staging (kb 0..7) ----
    if (l == 0) {
#pragma unroll
      for (int i = 0; i < 2; ++i) {
        const int kb = i * 4 + wv;
        const int k0 = kb * 32 + ksub;
        const float* xs = x + ((size_t)m * 64 + t) * 256 + k0;
        half8 hv;
#pragma unroll
        for (int jj = 0; jj < 8; ++jj) hv[jj] = (_Float16)xs[jj];
        *(half8*)&aLds[(size_t)(kb * 64 + lane) * 8] = hv;
      }
    }

    // ---- merged poll: data + gate + backpressure in ONE batched round ----
    unsigned pend = ((l == 0) ? 0xF0u : 0xFFu) & ~ownMask;
    const bool bpNeed = (tid == 0 && l < 63 && t >= 2);
    bool bpOK = !bpNeed || bpCache >= (epb | (u32)(t - 2));
    const u32* pLow = Hw4 + (slotCur ? S4 : 0) +
                      (((size_t)(l > 0 ? l - 1 : 0) * 16 + m) * 256) + wv * 32 + ksub;
    const u32* pHigh = Hw4 + (slotPrev ? S4 : 0) +
                       (((size_t)l * 16 + m) * 256) + wv * 32 + ksub;
    int round = 0;
    while (pend || !bpOK) {
      const bool ready = (l == 0) || (plCache >= (epb | (u32)t));
      const bool didData = ready && pend;
      u32x4 gv[8], pv, bv;
      if (didData) {
        if (pend & 0x01u) GLD4(gv[0], pLow, 0);    // i=0 g=0
        if (pend & 0x02u) GLD4(gv[1], pLow, 16);   // i=0 g=1
        if (pend & 0x04u) GLD4(gv[2], pLow, 512);  // i=1 g=0
        if (pend & 0x08u) GLD4(gv[3], pLow, 528);  // i=1 g=1
        if (pend & 0x10u) GLD4(gv[4], pHigh, 0);   // i3=0 g=0
        if (pend & 0x20u) GLD4(gv[5], pHigh, 16);  // i3=0 g=1
        if (pend & 0x40u) GLD4(gv[6], pHigh, 512); // i3=1 g=0
        if (pend & 0x80u) GLD4(gv[7], pHigh, 528); // i3=1 g=1
      }
      const bool didGate = (l > 0) && !ready;
      if (didGate) GLD4(pv, plBase, 0);
      if (!bpOK) GLD4(bv, bpBase, 0);
      asm volatile("s_waitcnt vmcnt(0)" ::: "memory");
      __builtin_amdgcn_sched_barrier(0);
      if (didGate) plCache = min4(pv);
      if (!bpOK) {
        bpCache = min4(bv);
        bpOK = bpCache >= (epb | (u32)(t - 2));
      }
      if (didData) {
#pragma unroll
        for (int b = 0; b < 8; ++b) {
          if ((pend >> b) & 1u) {
            const u32 exp_ = (b < 4) ? expIn : expOwn;
            const u32x4 v = gv[b];
            if ((v[0] >> 16) == exp_ && (v[1] >> 16) == exp_ &&
                (v[2] >> 16) == exp_ && (v[3] >> 16) == exp_) {
              const int kb = (b >> 1) * 4 + wv;
              u32* dp = (u32*)&aLds[(size_t)(kb * 64 + lane) * 8 + (b & 1) * 4];
              dp[0] = (v[0] & 0xFFFFu) | (v[1] << 16);
              dp[1] = (v[2] & 0xFFFFu) | (v[3] << 16);
              pend &= ~(1u << b);
            }
          }
        }
      }
      if (pend || !bpOK) {
        if (++round > 500000) break;  // hang guard: fail visibly, not dead
        if (!ready) __builtin_amdgcn_s_sleep(4);          // fill-phase damping
        else if (round > 64 && (round & 3) == 0) __builtin_amdgcn_s_sleep(1);
      }
    }
    __syncthreads();
    if (tid == 0)
      __hip_atomic_store(&prog[l * 4 + r], epb | (u32)t, __ATOMIC_RELAXED, SC_AGENT);

    // ---- GEMM: z[16 x 256slice] = A[16x512] * Wslice[512x256] ----
    f32x4 acc[4] = {{0.f, 0.f, 0.f, 0.f}, {0.f, 0.f, 0.f, 0.f},
                    {0.f, 0.f, 0.f, 0.f}, {0.f, 0.f, 0.f, 0.f}};
#pragma unroll
    for (int kb = 0; kb < 16; ++kb) {
      half8 a = *(const half8*)&aLds[(kb * 64 + lane) * 8];
#pragma unroll
      for (int q = 0; q < 4; ++q)
        acc[q] = __builtin_amdgcn_mfma_f32_16x16x32_f16(a, wreg[q * 16 + kb], acc[q], 0, 0, 0);
    }
    __syncthreads();  // aLds reads done -> publish may ds_write next-step slots

    // ---- 4x4 lane-group butterfly + epilogue + publish (global + ds_write) ----
#pragma unroll
    for (int q = 0; q < 4; ++q) {
      float v0 = acc[q][0], v1 = acc[q][1], v2 = acc[q][2], v3 = acc[q][3];
      float e0 = __shfl_xor(v1, 1, 64), e1 = __shfl_xor(v0, 1, 64);
      float e2 = __shfl_xor(v3, 1, 64), e3 = __shfl_xor(v2, 1, 64);
      const bool o1 = (lane & 1);
      float m0 = o1 ? e0 : v0, m1 = o1 ? v1 : e1;
      float m2 = o1 ? e2 : v2, m3 = o1 ? v3 : e3;
      float f0 = __shfl_xor(m2, 2, 64), f1 = __shfl_xor(m3, 2, 64);
      float f2 = __shfl_xor(m0, 2, 64), f3 = __shfl_xor(m1, 2, 64);
      const bool o2 = (lane & 2);
      float gI = o2 ? f0 : m0, gJ = o2 ? f1 : m1;
      float gF = o2 ? m2 : f2, gO = o2 ? m3 : f3;

      const float iv = gI + bI[q], jv = gJ + bJ[q];
      const float fv = gF + bF[q], ov = gO + bO[q];
      const float nc = sigm(fv + 1.0f) * creg[q] + sigm(iv) * tanh_(jv);
      const float nh = sigm(ov) * tanh_(nc);
      creg[q] = nc;
      union { _Float16 f; unsigned short s; } cv;
      cv.f = (_Float16)nh;
      const int gu = gu_q[q];
      const size_t idx = (slotCur ? S4 : 0) +
                         ((size_t)l * 16 + m_own) * 256 + gu;
      __hip_atomic_store(Hw4 + idx, (u32)cv.s | (expIn << 16),
                         __ATOMIC_RELAXED, SC_AGENT);
      // own-slice shortcut: next step's k-high staging slot, direct in LDS
      aLds[(size_t)((8 + (gu >> 5)) * 64 + ((((gu & 31) >> 3) << 4) | m_own)) * 8 +
           (gu & 7)] = cv.f;
      if (l == 63) out[((size_t)m_own * 64 + t) * 256 + gu] = nh;
    }
    // no trailing barrier: next iter's post-poll barrier orders aLds epochs
  }
}

extern "C" void kernel_launch(void* const* d_in, const int* in_sizes, int n_in,
                              void* d_out, int out_size, void* d_ws,
                              size_t ws_size, hipStream_t stream) {
  const float* x          = (const float*)d_in[0];
  const float* init_state = (const float*)d_in[1];
  const float* W          = (const float*)d_in[2];
  const float* bias       = (const float*)d_in[3];
  float* out = (float*)d_out;
  char* ws   = (char*)d_ws;

  bump_epoch<<<1, 1, 0, stream>>>(ws);
  init_ws<<<256, 256, 0, stream>>>(init_state, ws);
  lstm_mfma<<<256, 256, 0, stream>>>(x, init_state, W, bias, out, ws);
}

// Round 8
// 682.267 us; speedup vs baseline: 1.0055x; 1.0055x over previous
//
#include <hip/hip_runtime.h>

typedef _Float16 half8 __attribute__((ext_vector_type(8)));
typedef float f32x4 __attribute__((ext_vector_type(4)));
typedef unsigned int u32;
typedef unsigned int u32x4 __attribute__((ext_vector_type(4)));

#define SC_AGENT __HIP_MEMORY_SCOPE_AGENT

// Problem: B=16, T=64, L=64, H=256. K=2H=512, N=4H=1024.
//
// Round 8: COALESCED poll + publish (same tag protocol as R6/R7).
//   Previous rounds polled with 1KB-strided gathers (64 transactions per
//   GLD4 instruction, ~2048 16B IC transactions per WG-round) and published
//   with ~1024 scattered 4B stores -- the serialization + fabric congestion
//   was the protocol-insensitive ~4us term. This round:
//   - poll: lane L reads words [4L,4L+4) of the contiguous 16KB (l,slot)
//     block, sweeping b; each GLD4 = one 1KB burst. Tag-check, then LDS
//     scatter into aLds (banked, cheap).
//   - publish: epilogue -> hLds[16][68] -> barrier -> ONE tagged coalesced
//     global_store_dwordx4 per thread (16 rows x 256B contiguous).
//
//   h words: [h f16 | tag16], tag16 = (ep<<7)|t (t=0..63; 127 = h(l,-1) init).
//   All cross-WG traffic sc0 sc1 (IC truth) -- placement-independent, G16-safe.
//
//   aLds staging identity (from GEMM reads): A[m][k] lives at f16 index
//     ((k>>5)*64 + ((k&31)>>3)*16 + m)*8 + (k&7)
//   Poll word (b, u) (k = u for k-low, k = 256+u for k-high) -> index above
//   with m=b. A GLD4's 4 words (b, u0..u0+3), u0=lane*4 -> 4 consecutive f16
//   at one 8B-aligned slot -> two u32 LDS writes.
//   Own slice (u in [64r,64r+64)) never polled: threads with lane>>4==r skip
//   all k-high sweeps (their u is own-slice for every b); supplied by
//   epilogue ds_write (R7 shortcut) + t=0 prologue seed.
//
// ws: prog[256] u32 @0 (idx l*4+r); epoch u32 @4096; Hw4 @64KB:
//     u32[2 slots][64 l][16 b][256 u] = 2 MB.
constexpr size_t OFF_PROG  = 0;
constexpr size_t OFF_EPOCH = 4096;
constexpr size_t OFF_H     = 65536;
constexpr size_t S4 = (size_t)64 * 16 * 256;  // u32 words per slot

__device__ __forceinline__ float sigm(float v) { return 1.0f / (1.0f + __expf(-v)); }
__device__ __forceinline__ float tanh_(float v) { return 1.0f - 2.0f / (__expf(2.0f * v) + 1.0f); }
__device__ __forceinline__ u32 min4(u32x4 v) {
  u32 a = v[0] < v[1] ? v[0] : v[1];
  u32 b = v[2] < v[3] ? v[2] : v[3];
  return a < b ? a : b;
}

// Async IC loads: MUST be followed by s_waitcnt vmcnt(0) + sched_barrier(0)
// before reading dst (rule #18). OFS literal in [-4096, 4095].
#define GLD4(dst, base, OFS)                                                  \
  asm volatile("global_load_dwordx4 %0, %1, off offset:" #OFS " sc0 sc1"      \
               : "=v"(dst) : "v"(base))

// ---------------- epoch bump: ep cycles 1..511 ----------------
__global__ void bump_epoch(char* ws) {
  u32* ep = (u32*)(ws + OFF_EPOCH);
  u32 v = __hip_atomic_load(ep, __ATOMIC_RELAXED, SC_AGENT);
  u32 n = (v + 1) & 0x1FFu;
  if (n == 0) n = 1;
  __hip_atomic_store(ep, n, __ATOMIC_RELAXED, SC_AGENT);
}

// ---------------- init: prog=epb-1, slot0 tag 0 (never matches, ep>=1),
// slot1 = h(l,-1) with tag epb|127 ----------------
__global__ void init_ws(const float* __restrict__ init_state, char* ws) {
  u32* prog = (u32*)(ws + OFF_PROG);
  u32* Hw4 = (u32*)(ws + OFF_H);
  const u32 ep = __hip_atomic_load((u32*)(ws + OFF_EPOCH), __ATOMIC_RELAXED, SC_AGENT);
  const u32 epb = (ep & 0x1FFu) << 7;  // ep in [1,511] -> epb >= 128
  const int tid = blockIdx.x * 256 + threadIdx.x;  // 65536 threads
  if (tid < 256) prog[tid] = epb - 1u;  // < epb|t for all t
  const u32 tagInit = (epb | 127u) << 16;
  for (int e = tid; e < 64 * 16 * 256; e += 65536) {
    const int u = e & 255, b = (e >> 8) & 15, l = e >> 12;
    const size_t idx = ((size_t)l * 16 + b) * 256 + u;
    Hw4[idx] = 0u;  // slot0: tag 0, never matches
    union { _Float16 f; unsigned short s; } hv;
    hv.f = (_Float16)init_state[((l * 2 + 1) * 16 + b) * 256 + u];
    Hw4[S4 + idx] = (u32)hv.s | tagInit;
  }
}

// ---------------- main: 256 WGs = (layer l = wg>>2, slice r = wg&3) ----------------
__global__ __launch_bounds__(256, 1) void lstm_mfma(
    const float* __restrict__ x, const float* __restrict__ init_state,
    const float* __restrict__ W, const float* __restrict__ bias,
    float* __restrict__ out, char* ws) {
  u32* prog = (u32*)(ws + OFF_PROG);
  u32* Hw4 = (u32*)(ws + OFF_H);

  const int tid = threadIdx.x;
  const int wg = blockIdx.x;
  const int l = wg >> 2, r = wg & 3;
  const int wv = tid >> 6, lane = tid & 63;

  const u32 epb = (__hip_atomic_load((u32*)(ws + OFF_EPOCH), __ATOMIC_RELAXED,
                                     SC_AGENT) & 0x1FFu) << 7;

  __shared__ alignas(16) _Float16 aLds[16 * 64 * 8];  // A-frags, 16 KB
  __shared__ unsigned short hLds[16 * 68];            // publish repack, 2.1 KB

  // ---- W slice -> registers ----
  half8 wreg[64];
#pragma unroll
  for (int q = 0; q < 4; ++q) {
    const int nl = (wv * 4 + q) * 16 + (lane & 15);
    const int col = (nl & 3) * 256 + r * 64 + (nl >> 2);
#pragma unroll
    for (int kb = 0; kb < 16; ++kb) {
      const int k0 = kb * 32 + (lane >> 4) * 8;
      const float* src = W + (size_t)k0 * 1024 + col;
      half8 hv;
#pragma unroll
      for (int jj = 0; jj < 8; ++jj) hv[jj] = (_Float16)src[(size_t)jj * 1024];
      wreg[q * 16 + kb] = hv;
    }
  }

  // ---- per-thread epilogue identity (post-butterfly): per q-tile this thread
  // owns (unit u_q in [0,64) slice-local, batch m_own), all 4 gates in-lane.
  const int m_own = (lane >> 4) * 4 + (lane & 3);
  int uo_q[4];
  float creg[4], bI[4], bJ[4], bF[4], bO[4];
#pragma unroll
  for (int q = 0; q < 4; ++q) {
    uo_q[q] = (wv * 4 + q) * 4 + ((lane & 15) >> 2);  // unit in slice [0,64)
    const int gu = r * 64 + uo_q[q];
    creg[q] = init_state[((l * 2 + 0) * 16 + m_own) * 256 + gu];
    bI[q] = bias[0 * 256 + gu];
    bJ[q] = bias[1 * 256 + gu];
    bF[q] = bias[2 * 256 + gu];
    bO[q] = bias[3 * 256 + gu];
  }

  // ---- prologue: seed own-slice h(l,-1) into aLds (staging identity, k=256+u) ----
#pragma unroll
  for (int q = 0; q < 4; ++q) {
    const int gu = r * 64 + uo_q[q];
    const float h0 = init_state[((l * 2 + 1) * 16 + m_own) * 256 + gu];
    aLds[(size_t)((8 + (gu >> 5)) * 64 + (((gu & 31) >> 3) << 4) + m_own) * 8 +
         (gu & 7)] = (_Float16)h0;
  }

  // ---- coalesced poll geometry: thread owns u0 = lane*4 (fixed), sweeps b =
  // s*4+wv (s=0..3). Per-sweep address stride = 1024 words = 4096 B. Two base
  // pointers per half at +1024/+3072 words; offsets {-4096, 0}.
  const int u0 = lane * 4;
  // aLds f16 index base: idx(hf,s) = idxB + hf*4096 + s*32
  const int idxB = (u0 >> 5) * 512 + (((u0 & 31) >> 3) * 16 + wv) * 8 + (u0 & 7);
  // own-slice k-high skip: this thread's u0 lies in own slice <=> lane>>4 == r
  const u32 ownMask = ((lane >> 4) == r) ? 0xF0u : 0u;

  u32 plCache = 0, bpCache = 0;  // cached prog gates (monotone within launch)
  u32* const plBase = &prog[(l > 0 ? l - 1 : 0) * 4];
  u32* const bpBase = &prog[(l < 63 ? l + 1 : 63) * 4];

  const int m = lane & 15;          // x-staging role (unchanged mapping)
  const int ksub = (lane >> 4) * 8;

  for (int t = 0; t < 64; ++t) {
    const int slotCur = t & 1, slotPrev = (t + 1) & 1;
    const u32 expIn = epb | (u32)t;                               // h(l-1,t)
    const u32 expOwn = (t > 0) ? (epb | (u32)(t - 1)) : (epb | 127u);

    // ---- l==0: x staging (kb 0..7), old scatter mapping (off critical path) ----
    if (l == 0) {
#pragma unroll
      for (int i = 0; i < 2; ++i) {
        const int kb = i * 4 + wv;
        const int k0 = kb * 32 + ksub;
        const float* xs = x + ((size_t)m * 64 + t) * 256 + k0;
        half8 hv;
#pragma unroll
        for (int jj = 0; jj < 8; ++jj) hv[jj] = (_Float16)xs[jj];
        *(half8*)&aLds[(size_t)(kb * 64 + lane) * 8] = hv;
      }
    }

    // ---- merged poll: coalesced data + gate + backpressure, one vmcnt ----
    unsigned pend = ((l == 0) ? 0xF0u : 0xFFu) & ~ownMask;
    const bool bpNeed = (tid == 0 && l < 63 && t >= 2);
    bool bpOK = !bpNeed || bpCache >= (epb | (u32)(t - 2));
    const u32* pLa = Hw4 + (slotCur ? S4 : 0) +
                     ((size_t)(l > 0 ? l - 1 : 0) << 12) + wv * 256 + u0 + 1024;
    const u32* pLb = pLa + 2048;
    const u32* pHa = Hw4 + (slotPrev ? S4 : 0) + ((size_t)l << 12) + wv * 256 + u0 + 1024;
    const u32* pHb = pHa + 2048;
    int round = 0;
    while (pend || !bpOK) {
      const bool ready = (l == 0) || (plCache >= (epb | (u32)t));
      const bool didData = ready && pend;
      u32x4 gv[8], pv, bv;
      if (didData) {
        if (pend & 0x01u) GLD4(gv[0], pLa, -4096);  // k-low  s=0 (b=wv)
        if (pend & 0x02u) GLD4(gv[1], pLa, 0);      // k-low  s=1 (b=4+wv)
        if (pend & 0x04u) GLD4(gv[2], pLb, -4096);  // k-low  s=2
        if (pend & 0x08u) GLD4(gv[3], pLb, 0);      // k-low  s=3
        if (pend & 0x10u) GLD4(gv[4], pHa, -4096);  // k-high s=0
        if (pend & 0x20u) GLD4(gv[5], pHa, 0);      // k-high s=1
        if (pend & 0x40u) GLD4(gv[6], pHb, -4096);  // k-high s=2
        if (pend & 0x80u) GLD4(gv[7], pHb, 0);      // k-high s=3
      }
      const bool didGate = (l > 0) && !ready;
      if (didGate) GLD4(pv, plBase, 0);
      if (!bpOK) GLD4(bv, bpBase, 0);
      asm volatile("s_waitcnt vmcnt(0)" ::: "memory");
      __builtin_amdgcn_sched_barrier(0);
      if (didGate) plCache = min4(pv);
      if (!bpOK) {
        bpCache = min4(bv);
        bpOK = bpCache >= (epb | (u32)(t - 2));
      }
      if (didData) {
#pragma unroll
        for (int bit = 0; bit < 8; ++bit) {
          if ((pend >> bit) & 1u) {
            const u32 exp_ = (bit < 4) ? expIn : expOwn;
            const u32x4 v = gv[bit];
            if ((v[0] >> 16) == exp_ && (v[1] >> 16) == exp_ &&
                (v[2] >> 16) == exp_ && (v[3] >> 16) == exp_) {
              const int hf = bit >> 2, s = bit & 3;
              u32* dp = (u32*)&aLds[idxB + hf * 4096 + s * 32];
              dp[0] = (v[0] & 0xFFFFu) | (v[1] << 16);
              dp[1] = (v[2] & 0xFFFFu) | (v[3] << 16);
              pend &= ~(1u << bit);
            }
          }
        }
      }
      if (pend || !bpOK) {
        if (++round > 500000) break;  // hang guard: fail visibly, not dead
        if (!ready) __builtin_amdgcn_s_sleep(4);          // fill-phase damping
        else if (round > 64 && (round & 3) == 0) __builtin_amdgcn_s_sleep(1);
      }
    }
    __syncthreads();
    if (tid == 0)
      __hip_atomic_store(&prog[l * 4 + r], epb | (u32)t, __ATOMIC_RELAXED, SC_AGENT);

    // ---- GEMM: z[16 x 256slice] = A[16x512] * Wslice[512x256] ----
    f32x4 acc[4] = {{0.f, 0.f, 0.f, 0.f}, {0.f, 0.f, 0.f, 0.f},
                    {0.f, 0.f, 0.f, 0.f}, {0.f, 0.f, 0.f, 0.f}};
#pragma unroll
    for (int kb = 0; kb < 16; ++kb) {
      half8 a = *(const half8*)&aLds[(kb * 64 + lane) * 8];
#pragma unroll
      for (int q = 0; q < 4; ++q)
        acc[q] = __builtin_amdgcn_mfma_f32_16x16x32_f16(a, wreg[q * 16 + kb], acc[q], 0, 0, 0);
    }
    __syncthreads();  // aLds reads done -> epilogue may ds_write next-step slots

    // ---- butterfly + epilogue: own-slice aLds + hLds repack ----
#pragma unroll
    for (int q = 0; q < 4; ++q) {
      float v0 = acc[q][0], v1 = acc[q][1], v2 = acc[q][2], v3 = acc[q][3];
      float e0 = __shfl_xor(v1, 1, 64), e1 = __shfl_xor(v0, 1, 64);
      float e2 = __shfl_xor(v3, 1, 64), e3 = __shfl_xor(v2, 1, 64);
      const bool o1 = (lane & 1);
      float m0 = o1 ? e0 : v0, m1 = o1 ? v1 : e1;
      float m2 = o1 ? e2 : v2, m3 = o1 ? v3 : e3;
      float f0 = __shfl_xor(m2, 2, 64), f1 = __shfl_xor(m3, 2, 64);
      float f2 = __shfl_xor(m0, 2, 64), f3 = __shfl_xor(m1, 2, 64);
      const bool o2 = (lane & 2);
      float gI = o2 ? f0 : m0, gJ = o2 ? f1 : m1;
      float gF = o2 ? m2 : f2, gO = o2 ? m3 : f3;

      const float iv = gI + bI[q], jv = gJ + bJ[q];
      const float fv = gF + bF[q], ov = gO + bO[q];
      const float nc = sigm(fv + 1.0f) * creg[q] + sigm(iv) * tanh_(jv);
      const float nh = sigm(ov) * tanh_(nc);
      creg[q] = nc;
      union { _Float16 f; unsigned short s; } cv;
      cv.f = (_Float16)nh;
      const int gu = r * 64 + uo_q[q];
      // own-slice shortcut: next step's k-high staging slot, direct in LDS
      aLds[(size_t)((8 + (gu >> 5)) * 64 + (((gu & 31) >> 3) << 4) + m_own) * 8 +
           (gu & 7)] = cv.f;
      hLds[m_own * 68 + uo_q[q]] = cv.s;
      if (l == 63) out[((size_t)m_own * 64 + t) * 256 + gu] = nh;
    }
    __syncthreads();  // hLds complete -> coalesced publish

    // ---- publish: ONE tagged coalesced dwordx4 per thread ----
    {
      const int sb = tid >> 4, so0 = (tid & 15) * 4;
      u32x4 pub;
#pragma unroll
      for (int j = 0; j < 4; ++j)
        pub[j] = (u32)hLds[sb * 68 + so0 + j] | (expIn << 16);
      u32* dst = Hw4 + (slotCur ? S4 : 0) + ((size_t)l << 12) + sb * 256 + r * 64 + so0;
      asm volatile("global_store_dwordx4 %0, %1, off sc0 sc1"
                   :: "v"(dst), "v"(pub) : "memory");
    }
    // no trailing barrier: next iter's post-poll barrier orders aLds/hLds epochs
  }
}

extern "C" void kernel_launch(void* const* d_in, const int* in_sizes, int n_in,
                              void* d_out, int out_size, void* d_ws,
                              size_t ws_size, hipStream_t stream) {
  const float* x          = (const float*)d_in[0];
  const float* init_state = (const float*)d_in[1];
  const float* W          = (const float*)d_in[2];
  const float* bias       = (const float*)d_in[3];
  float* out = (float*)d_out;
  char* ws   = (char*)d_ws;

  bump_epoch<<<1, 1, 0, stream>>>(ws);
  init_ws<<<256, 256, 0, stream>>>(init_state, ws);
  lstm_mfma<<<256, 256, 0, stream>>>(x, init_state, W, bias, out, ws);
}